// Round 3
// baseline (235.253 us; speedup 1.0000x reference)
//
#include <hip/hip_runtime.h>
#include <hip/hip_bf16.h>

// Hmoe: gate = sigmoid(x @ w + b); tree-product over 6 levels -> P (32768 x 64);
// out = P @ responses.
// Kernel 0a: convert+transpose responses -> RT bf16 [2048][64] (ws)
// Kernel 0b: convert+transpose w -> wTh/wTl bf16 [64][2048] hi/lo split (ws)
// Kernel 1: gate GEMM, BM=64 (4 waves x 16 rows) -> 512 blocks = 2 blocks/CU
//           for latency hiding. A-frags from global f32 (cvt_pk to bf16 in
//           regs), B-frags from global bf16 (L1-broadcast across waves).
//           No barriers in K-loop. Epilogue: sigmoid -> LDS -> tree -> P bf16.
// Kernel 2: out = P @ RT via bf16 MFMA, f32 out.

typedef short bf16x8 __attribute__((ext_vector_type(8)));
typedef float f32x4  __attribute__((ext_vector_type(4)));

#define BS    32768
#define DIMX  2048
#define NODES 63
#define NL    64
#define DIMY  2048

__device__ __forceinline__ unsigned short f2bf(float f) {
    union { float f; unsigned int u; } v; v.f = f;
    unsigned int r = v.u + 0x7FFFu + ((v.u >> 16) & 1u);   // RNE
    return (unsigned short)(r >> 16);
}
__device__ __forceinline__ float bf2f(unsigned short h) {
    union { float f; unsigned int u; } v; v.u = ((unsigned int)h) << 16;
    return v.f;
}

// ---------------- kernel 0a: responses f32 [64][2048] -> RT bf16 [2048][64] ---
__global__ __launch_bounds__(256) void rt_conv(const float* __restrict__ R,
                                               unsigned short* __restrict__ RT) {
    int f = blockIdx.x * 256 + threadIdx.x;     // 131072 total
    int n = f >> 6;
    int k = f & 63;
    RT[f] = f2bf(R[k * DIMY + n]);
}

// ---------------- kernel 0b: w f32 [2048][63] -> wT hi/lo bf16 [64][2048] -----
__global__ __launch_bounds__(256) void wt_conv(const float* __restrict__ w,
                                               unsigned short* __restrict__ wTh,
                                               unsigned short* __restrict__ wTl) {
    int f = blockIdx.x * 256 + threadIdx.x;     // 64*2048 total
    int n = f >> 11;                            // node 0..63
    int k = f & 2047;
    float v = (n < NODES) ? w[(size_t)k * NODES + n] : 0.0f;
    unsigned short h = f2bf(v);
    wTh[f] = h;
    wTl[f] = f2bf(v - bf2f(h));
}

// ---------------- kernel 1: gates + tree -> P --------------------------------
#define BM 64       // rows per block: 4 waves x 1 row-frag x 16

__device__ __forceinline__ bf16x8 pack8(float4 a, float4 b) {
    union { __hip_bfloat162 h2[4]; bf16x8 v; } u;
    u.h2[0] = __float22bfloat162_rn(make_float2(a.x, a.y));
    u.h2[1] = __float22bfloat162_rn(make_float2(a.z, a.w));
    u.h2[2] = __float22bfloat162_rn(make_float2(b.x, b.y));
    u.h2[3] = __float22bfloat162_rn(make_float2(b.z, b.w));
    return u.v;
}

__global__ __launch_bounds__(256) void gate_kernel(const float* __restrict__ x,
                                                   const unsigned short* __restrict__ wTh,
                                                   const unsigned short* __restrict__ wTl,
                                                   const float* __restrict__ bias,
                                                   unsigned short* __restrict__ P) {
    __shared__ float gl[BM][NL + 1];            // gates, +1 pad (16.6 KB)

    const int t    = threadIdx.x;
    const int lane = t & 63;
    const int wv   = t >> 6;        // 4 waves
    const int lr   = lane & 15;
    const int lg   = lane >> 4;
    const int m0   = blockIdx.x * BM;
    const int r0   = wv * 16;       // each wave owns 16 rows

    f32x4 acc[4];
    #pragma unroll
    for (int cf = 0; cf < 4; ++cf) acc[cf] = (f32x4){0.f, 0.f, 0.f, 0.f};

    const float* xp = x + (size_t)(m0 + r0 + lr) * DIMX + lg * 8;
    const unsigned short* bh0 = wTh + (size_t)lr * DIMX + lg * 8;
    const unsigned short* bl0 = wTl + (size_t)lr * DIMX + lg * 8;

    #pragma unroll 8
    for (int kk = 0; kk < DIMX; kk += 32) {
        float4 v0 = *(const float4*)(xp + kk);
        float4 v1 = *(const float4*)(xp + kk + 4);
        bf16x8 a = pack8(v0, v1);
        #pragma unroll
        for (int cf = 0; cf < 4; ++cf) {
            const size_t nb = (size_t)(cf * 16) * DIMX + kk;
            bf16x8 bh = *(const bf16x8*)(bh0 + nb);
            bf16x8 bo = *(const bf16x8*)(bl0 + nb);
            acc[cf] = __builtin_amdgcn_mfma_f32_16x16x32_bf16(a, bh, acc[cf], 0, 0, 0);
            acc[cf] = __builtin_amdgcn_mfma_f32_16x16x32_bf16(a, bo, acc[cf], 0, 0, 0);
        }
    }

    // bias + sigmoid -> gates in LDS.  D-frag: row=(lane>>4)*4+reg, col=lane&15.
    #pragma unroll
    for (int cf = 0; cf < 4; ++cf) {
        const int col = cf * 16 + lr;
        const float bb = bias[col < NODES ? col : 0];   // col 63 unused downstream
        #pragma unroll
        for (int i = 0; i < 4; ++i) {
            int row = r0 + lg * 4 + i;
            float s = acc[cf][i] + bb;
            gl[row][col] = 1.0f / (1.0f + __expf(-s));
        }
    }
    __syncthreads();

    // leaf probabilities: 4 threads per row; leaf L = m + 16*b4 + 32*b5, m=0..15
    {
        const int rr = t >> 2;          // 0..63
        const int b4 = t & 1, b5 = (t >> 1) & 1;
        const float* g = gl[rr];
        float a2[2], a4[4], a8[8], a16[16];
        float g0 = g[0];
        a2[0] = g0; a2[1] = 1.f - g0;
        #pragma unroll
        for (int m = 0; m < 4; ++m) {
            float gg = g[1 + (m & 1)];
            a4[m] = a2[m & 1] * ((m & 2) ? (1.f - gg) : gg);
        }
        #pragma unroll
        for (int m = 0; m < 8; ++m) {
            float gg = g[3 + (m & 3)];
            a8[m] = a4[m & 3] * ((m & 4) ? (1.f - gg) : gg);
        }
        #pragma unroll
        for (int m = 0; m < 16; ++m) {
            float gg = g[7 + (m & 7)];
            a16[m] = a8[m & 7] * ((m & 8) ? (1.f - gg) : gg);
        }
        unsigned short o[16];
        #pragma unroll
        for (int m = 0; m < 16; ++m) {
            float p = a16[m];
            float g5 = g[15 + m];                 // level 5: node 15 + (L&15)
            p *= b4 ? (1.f - g5) : g5;
            float g6 = g[31 + m + 16 * b4];       // level 6: node 31 + (L&31)
            p *= b5 ? (1.f - g6) : g6;
            o[m] = f2bf(p);
        }
        uint4 q0, q1;
        q0.x = (unsigned)o[0]  | ((unsigned)o[1]  << 16);
        q0.y = (unsigned)o[2]  | ((unsigned)o[3]  << 16);
        q0.z = (unsigned)o[4]  | ((unsigned)o[5]  << 16);
        q0.w = (unsigned)o[6]  | ((unsigned)o[7]  << 16);
        q1.x = (unsigned)o[8]  | ((unsigned)o[9]  << 16);
        q1.y = (unsigned)o[10] | ((unsigned)o[11] << 16);
        q1.z = (unsigned)o[12] | ((unsigned)o[13] << 16);
        q1.w = (unsigned)o[14] | ((unsigned)o[15] << 16);
        uint4* dst = (uint4*)&P[(size_t)(m0 + rr) * NL + 16 * b4 + 32 * b5];
        dst[0] = q0;
        dst[1] = q1;
    }
}

// ---------------- kernel 2: out = P @ RT^T (P: MxK=64, RT: [n][k]) -----------
#define OBM  128
#define OBN  128
#define OLD  72

__global__ __launch_bounds__(256) void out_kernel(const unsigned short* __restrict__ P,
                                                  const unsigned short* __restrict__ RT,
                                                  float* __restrict__ out) {
    __shared__ __align__(16) unsigned short ps[OBM][OLD];
    __shared__ __align__(16) unsigned short rs[OBN][OLD];
    const int t  = threadIdx.x;
    const int n0 = blockIdx.x * OBN;
    const int m0 = blockIdx.y * OBM;

    #pragma unroll
    for (int p = 0; p < 4; ++p) {
        int c   = p * 256 + t;
        int row = c >> 3;
        int c8  = c & 7;
        *(uint4*)&ps[row][c8 * 8] = *(const uint4*)&P [(size_t)(m0 + row) * NL + c8 * 8];
        *(uint4*)&rs[row][c8 * 8] = *(const uint4*)&RT[(size_t)(n0 + row) * NL + c8 * 8];
    }
    __syncthreads();

    const int lane = t & 63;
    const int wv   = t >> 6;
    const int wm   = (wv >> 1) * 64;   // wave tile 64x64
    const int wn   = (wv & 1) * 64;
    const int lr   = lane & 15;
    const int lg   = lane >> 4;

    f32x4 acc[4][4];
    #pragma unroll
    for (int rf = 0; rf < 4; ++rf)
        #pragma unroll
        for (int cf = 0; cf < 4; ++cf) acc[rf][cf] = (f32x4){0.f, 0.f, 0.f, 0.f};

    #pragma unroll
    for (int kk = 0; kk < NL; kk += 32) {
        bf16x8 a[4], bb[4];
        #pragma unroll
        for (int rf = 0; rf < 4; ++rf)
            a[rf] = *(const bf16x8*)&ps[wm + rf * 16 + lr][kk + lg * 8];
        #pragma unroll
        for (int cf = 0; cf < 4; ++cf)
            bb[cf] = *(const bf16x8*)&rs[wn + cf * 16 + lr][kk + lg * 8];
        #pragma unroll
        for (int rf = 0; rf < 4; ++rf)
            #pragma unroll
            for (int cf = 0; cf < 4; ++cf)
                acc[rf][cf] = __builtin_amdgcn_mfma_f32_16x16x32_bf16(a[rf], bb[cf],
                                                                      acc[rf][cf], 0, 0, 0);
    }

    #pragma unroll
    for (int rf = 0; rf < 4; ++rf) {
        #pragma unroll
        for (int cf = 0; cf < 4; ++cf) {
            #pragma unroll
            for (int i = 0; i < 4; ++i) {
                int row = m0 + wm + rf * 16 + lg * 4 + i;
                int col = n0 + wn + cf * 16 + lr;
                out[(size_t)row * DIMY + col] = acc[rf][cf][i];
            }
        }
    }
}

extern "C" void kernel_launch(void* const* d_in, const int* in_sizes, int n_in,
                              void* d_out, int out_size, void* d_ws, size_t ws_size,
                              hipStream_t stream) {
    const float* x = (const float*)d_in[0];
    const float* w = (const float*)d_in[1];
    const float* b = (const float*)d_in[2];
    const float* R = (const float*)d_in[3];
    float* out = (float*)d_out;

    char* ws = (char*)d_ws;
    unsigned short* P   = (unsigned short*)ws;                                  // 4 MB
    unsigned short* RT  = (unsigned short*)(ws + (size_t)BS * NL * 2);          // 256 KB
    unsigned short* wTh = (unsigned short*)(ws + (size_t)BS * NL * 2 + 262144); // 256 KB
    unsigned short* wTl = (unsigned short*)(ws + (size_t)BS * NL * 2 + 524288); // 256 KB

    rt_conv<<<dim3((NL * DIMY) / 256), 256, 0, stream>>>(R, RT);
    wt_conv<<<dim3((NL * DIMX) / 256), 256, 0, stream>>>(w, wTh, wTl);
    gate_kernel<<<dim3(BS / BM), 256, 0, stream>>>(x, wTh, wTl, b, P);
    out_kernel<<<dim3(DIMY / OBN, BS / OBM), 256, 0, stream>>>(P, RT, out);
}

// Round 4
// 150.141 us; speedup vs baseline: 1.5669x; 1.5669x over previous
//
#include <hip/hip_runtime.h>
#include <hip/hip_bf16.h>

// Hmoe: gate = sigmoid(x @ w + b); tree-product over 6 levels -> P (32768 x 64);
// out = P @ responses.
// Kernel 0a: responses -> RT bf16 [2048][64]
// Kernel 0b: w -> wTh/wTl bf16 [64][2048] hi/lo split
// Kernel 1: gate GEMM v4 — BM=32 (1024 blocks, ~5/CU), LDS-staged x and w
//           per K-step with coalesced loads; reg-prefetch one step ahead.
//           Fragments read from LDS (gathers in LDS, not global). Fused
//           sigmoid + tree epilogue -> P bf16.
// Kernel 2: out = P @ RT via bf16 MFMA, f32 out.

typedef short bf16x8 __attribute__((ext_vector_type(8)));
typedef float f32x4  __attribute__((ext_vector_type(4)));

#define BS    32768
#define DIMX  2048
#define NODES 63
#define NL    64
#define DIMY  2048

__device__ __forceinline__ unsigned short f2bf(float f) {
    union { float f; unsigned int u; } v; v.f = f;
    unsigned int r = v.u + 0x7FFFu + ((v.u >> 16) & 1u);   // RNE
    return (unsigned short)(r >> 16);
}
__device__ __forceinline__ float bf2f(unsigned short h) {
    union { float f; unsigned int u; } v; v.u = ((unsigned int)h) << 16;
    return v.f;
}

// ---------------- kernel 0a: responses f32 [64][2048] -> RT bf16 [2048][64] ---
__global__ __launch_bounds__(256) void rt_conv(const float* __restrict__ R,
                                               unsigned short* __restrict__ RT) {
    int f = blockIdx.x * 256 + threadIdx.x;     // 131072 total
    int n = f >> 6;
    int k = f & 63;
    RT[f] = f2bf(R[k * DIMY + n]);
}

// ---------------- kernel 0b: w f32 [2048][63] -> wT hi/lo bf16 [64][2048] -----
__global__ __launch_bounds__(256) void wt_conv(const float* __restrict__ w,
                                               unsigned short* __restrict__ wTh,
                                               unsigned short* __restrict__ wTl) {
    int f = blockIdx.x * 256 + threadIdx.x;     // 64*2048 total
    int n = f >> 11;                            // node 0..63
    int k = f & 2047;
    float v = (n < NODES) ? w[(size_t)k * NODES + n] : 0.0f;
    unsigned short h = f2bf(v);
    wTh[f] = h;
    wTl[f] = f2bf(v - bf2f(h));
}

// ---------------- kernel 1: gates + tree -> P --------------------------------
#define GBM   32
#define GBK   64
#define GLD   72                    // padded LDS row stride (bf16): 144 B
#define NSTEP (DIMX / GBK)          // 32

__device__ __forceinline__ bf16x8 pack8(float4 a, float4 b) {
    union { __hip_bfloat162 h2[4]; bf16x8 v; } u;
    u.h2[0] = __float22bfloat162_rn(make_float2(a.x, a.y));
    u.h2[1] = __float22bfloat162_rn(make_float2(a.z, a.w));
    u.h2[2] = __float22bfloat162_rn(make_float2(b.x, b.y));
    u.h2[3] = __float22bfloat162_rn(make_float2(b.z, b.w));
    return u.v;
}

__global__ __launch_bounds__(256, 5) void gate_kernel(const float* __restrict__ x,
                                                      const unsigned short* __restrict__ wTh,
                                                      const unsigned short* __restrict__ wTl,
                                                      const float* __restrict__ bias,
                                                      unsigned short* __restrict__ P) {
    __shared__ __align__(16) unsigned short xs[GBM][GLD];   // 4.6 KB
    __shared__ __align__(16) unsigned short wsh[NL][GLD];   // 9.2 KB
    __shared__ __align__(16) unsigned short wsl[NL][GLD];   // 9.2 KB
    __shared__ float gl[GBM][NL + 1];                       // 8.3 KB

    const int t    = threadIdx.x;
    const int lane = t & 63;
    const int wv   = t >> 6;        // 4 waves
    const int lr   = lane & 15;
    const int lg   = lane >> 4;
    const int m0   = blockIdx.x * GBM;
    const int rm   = wv & 1;        // row-frag half (16 rows)
    const int cfp  = wv >> 1;       // col-frag pair (32 cols)

    // ---- staging index map (all coalesced, 16B/lane) ----
    const int xr = t >> 3;                // x: row 0..31
    const int xc = (t & 7) * 8;           //    col 0..56 step 8 (8 floats/thread)
    const float* xsrc = x + (size_t)(m0 + xr) * DIMX + xc;
    const int wrA = t >> 3;               // w rows 0..31 (uint4 = 8 bf16)
    const int wrB = wrA + 32;             // w rows 32..63
    const int wc  = (t & 7) * 8;
    const unsigned short* hA = wTh + (size_t)wrA * DIMX + wc;
    const unsigned short* hB = wTh + (size_t)wrB * DIMX + wc;
    const unsigned short* lA = wTl + (size_t)wrA * DIMX + wc;
    const unsigned short* lB = wTl + (size_t)wrB * DIMX + wc;

    // ---- prefetch step 0 into regs ----
    float4 rx0 = *(const float4*)(xsrc);
    float4 rx1 = *(const float4*)(xsrc + 4);
    uint4  rhA = *(const uint4*)(hA);
    uint4  rhB = *(const uint4*)(hB);
    uint4  rlA = *(const uint4*)(lA);
    uint4  rlB = *(const uint4*)(lB);

    f32x4 acc[2];
    acc[0] = (f32x4){0.f, 0.f, 0.f, 0.f};
    acc[1] = (f32x4){0.f, 0.f, 0.f, 0.f};

    for (int k = 0; k < NSTEP; ++k) {
        __syncthreads();                       // prev step's LDS reads complete
        *(bf16x8*)&xs[xr][xc]  = pack8(rx0, rx1);
        *(uint4*)&wsh[wrA][wc] = rhA;
        *(uint4*)&wsh[wrB][wc] = rhB;
        *(uint4*)&wsl[wrA][wc] = rlA;
        *(uint4*)&wsl[wrB][wc] = rlB;
        __syncthreads();                       // tile visible
        if (k + 1 < NSTEP) {                   // issue next loads; latency hides
            const int ko = (k + 1) * GBK;      // under compute + next barrier
            rx0 = *(const float4*)(xsrc + ko);
            rx1 = *(const float4*)(xsrc + ko + 4);
            rhA = *(const uint4*)(hA + ko);
            rhB = *(const uint4*)(hB + ko);
            rlA = *(const uint4*)(lA + ko);
            rlB = *(const uint4*)(lB + ko);
        }
        #pragma unroll
        for (int kk = 0; kk < GBK; kk += 32) {
            bf16x8 a = *(const bf16x8*)&xs[rm * 16 + lr][kk + lg * 8];
            #pragma unroll
            for (int ci = 0; ci < 2; ++ci) {
                const int brow = (cfp * 2 + ci) * 16 + lr;
                bf16x8 bh = *(const bf16x8*)&wsh[brow][kk + lg * 8];
                bf16x8 bo = *(const bf16x8*)&wsl[brow][kk + lg * 8];
                acc[ci] = __builtin_amdgcn_mfma_f32_16x16x32_bf16(a, bh, acc[ci], 0, 0, 0);
                acc[ci] = __builtin_amdgcn_mfma_f32_16x16x32_bf16(a, bo, acc[ci], 0, 0, 0);
            }
        }
    }

    // ---- bias + sigmoid -> gl.  D-frag: row=(lane>>4)*4+reg, col=lane&15. ----
    #pragma unroll
    for (int ci = 0; ci < 2; ++ci) {
        const int col = cfp * 32 + ci * 16 + lr;
        const float bb = bias[col < NODES ? col : 0];   // col 63 unread by tree
        #pragma unroll
        for (int i = 0; i < 4; ++i) {
            int row = rm * 16 + lg * 4 + i;
            float s = acc[ci][i] + bb;
            gl[row][col] = 1.0f / (1.0f + __expf(-s));
        }
    }
    __syncthreads();

    // ---- tree: 8 threads per row; each writes 8 leaves (16 B) ----
    {
        const int rr  = t >> 3;              // 0..31
        const int sub = t & 7;
        const int b5 = sub & 1, b4 = (sub >> 1) & 1, mh = sub >> 2;
        const float* g = gl[rr];
        float a2[2], a4[4], a8[8];
        float g0 = g[0];
        a2[0] = g0; a2[1] = 1.f - g0;
        #pragma unroll
        for (int m = 0; m < 4; ++m) {
            float gg = g[1 + (m & 1)];
            a4[m] = a2[m & 1] * ((m & 2) ? (1.f - gg) : gg);
        }
        #pragma unroll
        for (int m = 0; m < 8; ++m) {
            float gg = g[3 + (m & 3)];
            a8[m] = a4[m & 3] * ((m & 4) ? (1.f - gg) : gg);
        }
        unsigned short o[8];
        #pragma unroll
        for (int j = 0; j < 8; ++j) {
            int m = mh * 8 + j;
            float g4 = g[7 + j];                  // level 4 node: 7 + (m&7)
            float p  = a8[j] * (mh ? (1.f - g4) : g4);
            float g5 = g[15 + m];                 // level 5: 15 + (L&15)
            p *= b4 ? (1.f - g5) : g5;
            float g6 = g[31 + m + 16 * b4];       // level 6: 31 + (L&31)
            p *= b5 ? (1.f - g6) : g6;
            o[j] = f2bf(p);
        }
        uint4 q;
        q.x = (unsigned)o[0] | ((unsigned)o[1] << 16);
        q.y = (unsigned)o[2] | ((unsigned)o[3] << 16);
        q.z = (unsigned)o[4] | ((unsigned)o[5] << 16);
        q.w = (unsigned)o[6] | ((unsigned)o[7] << 16);
        *(uint4*)&P[(size_t)(m0 + rr) * NL + b5 * 32 + b4 * 16 + mh * 8] = q;
    }
}

// ---------------- kernel 2: out = P @ RT^T (P: MxK=64, RT: [n][k]) -----------
#define OBM  128
#define OBN  128
#define OLD  72

__global__ __launch_bounds__(256) void out_kernel(const unsigned short* __restrict__ P,
                                                  const unsigned short* __restrict__ RT,
                                                  float* __restrict__ out) {
    __shared__ __align__(16) unsigned short ps[OBM][OLD];
    __shared__ __align__(16) unsigned short rs[OBN][OLD];
    const int t  = threadIdx.x;
    const int n0 = blockIdx.x * OBN;
    const int m0 = blockIdx.y * OBM;

    #pragma unroll
    for (int p = 0; p < 4; ++p) {
        int c   = p * 256 + t;
        int row = c >> 3;
        int c8  = c & 7;
        *(uint4*)&ps[row][c8 * 8] = *(const uint4*)&P [(size_t)(m0 + row) * NL + c8 * 8];
        *(uint4*)&rs[row][c8 * 8] = *(const uint4*)&RT[(size_t)(n0 + row) * NL + c8 * 8];
    }
    __syncthreads();

    const int lane = t & 63;
    const int wv   = t >> 6;
    const int wm   = (wv >> 1) * 64;   // wave tile 64x64
    const int wn   = (wv & 1) * 64;
    const int lr   = lane & 15;
    const int lg   = lane >> 4;

    f32x4 acc[4][4];
    #pragma unroll
    for (int rf = 0; rf < 4; ++rf)
        #pragma unroll
        for (int cf = 0; cf < 4; ++cf) acc[rf][cf] = (f32x4){0.f, 0.f, 0.f, 0.f};

    #pragma unroll
    for (int kk = 0; kk < NL; kk += 32) {
        bf16x8 a[4], bb[4];
        #pragma unroll
        for (int rf = 0; rf < 4; ++rf)
            a[rf] = *(const bf16x8*)&ps[wm + rf * 16 + lr][kk + lg * 8];
        #pragma unroll
        for (int cf = 0; cf < 4; ++cf)
            bb[cf] = *(const bf16x8*)&rs[wn + cf * 16 + lr][kk + lg * 8];
        #pragma unroll
        for (int rf = 0; rf < 4; ++rf)
            #pragma unroll
            for (int cf = 0; cf < 4; ++cf)
                acc[rf][cf] = __builtin_amdgcn_mfma_f32_16x16x32_bf16(a[rf], bb[cf],
                                                                      acc[rf][cf], 0, 0, 0);
    }

    #pragma unroll
    for (int rf = 0; rf < 4; ++rf) {
        #pragma unroll
        for (int cf = 0; cf < 4; ++cf) {
            #pragma unroll
            for (int i = 0; i < 4; ++i) {
                int row = m0 + wm + rf * 16 + lg * 4 + i;
                int col = n0 + wn + cf * 16 + lr;
                out[(size_t)row * DIMY + col] = acc[rf][cf][i];
            }
        }
    }
}

extern "C" void kernel_launch(void* const* d_in, const int* in_sizes, int n_in,
                              void* d_out, int out_size, void* d_ws, size_t ws_size,
                              hipStream_t stream) {
    const float* x = (const float*)d_in[0];
    const float* w = (const float*)d_in[1];
    const float* b = (const float*)d_in[2];
    const float* R = (const float*)d_in[3];
    float* out = (float*)d_out;

    char* ws = (char*)d_ws;
    unsigned short* P   = (unsigned short*)ws;                                  // 4 MB
    unsigned short* RT  = (unsigned short*)(ws + (size_t)BS * NL * 2);          // 256 KB
    unsigned short* wTh = (unsigned short*)(ws + (size_t)BS * NL * 2 + 262144); // 256 KB
    unsigned short* wTl = (unsigned short*)(ws + (size_t)BS * NL * 2 + 524288); // 256 KB

    rt_conv<<<dim3((NL * DIMY) / 256), 256, 0, stream>>>(R, RT);
    wt_conv<<<dim3((NL * DIMX) / 256), 256, 0, stream>>>(w, wTh, wTl);
    gate_kernel<<<dim3(BS / GBM), 256, 0, stream>>>(x, wTh, wTl, b, P);
    out_kernel<<<dim3(DIMY / OBN, BS / OBM), 256, 0, stream>>>(P, RT, out);
}